// Round 8
// baseline (281.696 us; speedup 1.0000x reference)
//
#include <hip/hip_runtime.h>

// Problem constants: B=2, C=256, P=64 (NH=4, HD=16), H=W=64 -> N=4096, G=16.
#define B_ 2
#define C_ 256
#define P_ 64
#define N_ 4096
#define EPS_ 1e-5f
// SCALE * log2(e): softmax computed with exp2
#define QSCALE_ 0.3606737602222409f

typedef _Float16 half2 __attribute__((ext_vector_type(2)));
typedef _Float16 half4 __attribute__((ext_vector_type(4)));
typedef _Float16 half8 __attribute__((ext_vector_type(8)));
typedef float f32x4 __attribute__((ext_vector_type(4)));

// Schraudolph fast exp2: 2 full-rate VALU ops vs quarter-rate v_exp_f32.
static __device__ __forceinline__ float fexp2(float x) {
  return __builtin_bit_cast(float, (int)fmaf(x, 8388608.0f, 1064872512.0f));
}

static __device__ __forceinline__ half2 pack2(float a, float b) {
  return __builtin_bit_cast(half2, __builtin_amdgcn_cvt_pkrtz(a, b));
}

struct TP {
  const float* feat[3];
  const float* Wq[3]; const float* bq[3];
  const float* Wk[3]; const float* bk[3];
  const float* Wv[3]; const float* bv[3];
  const float* Wo[3]; const float* bo[3];
  const float* gm[3]; const float* bt[3];
  _Float16* xT;          // [3][2][4096][256] f16 transposed feats
  _Float16* q16;         // [3][2][4096][64]  q (then ao, in place)
  _Float16* k16;         // [3][8(b4h)][4096][16]
  _Float16* v16;         // [3][8][16][4096]
  _Float16* wq16[3];     // [64][256]
  _Float16* wk16[3];     // [64][512]
  _Float16* wv16[3];     // [64][512]
  _Float16* wo16[3];     // [256][64]
  float* stats;          // [3][2][16][2] {sum, sumsq}
  float* out;
  int ctx0[3]; int ctx1[3];
};

// ---------------------------------------------------------------------------
// Prep: feat fp32 [b][c][n] -> f16 xT [m][b][n][c] via LDS transpose so the
// global writes are 128B-contiguous. Also weight fp32->f16 + stats zero.
// grid (256, 2, 3): x = cblk*64 + nblk. block 256.
// ---------------------------------------------------------------------------
__global__ __launch_bounds__(256) void prep_kernel(TP P) {
  __shared__ _Float16 lt[64 * 72];  // [n][c] tile, row stride 72
  const int m = blockIdx.z, b = blockIdx.y;
  const int tid = threadIdx.x;
  const int cblk = blockIdx.x >> 6, nblk = blockIdx.x & 63;
  {
    const int n = nblk * 64 + (tid & 63);
    const int cb = (tid >> 6) * 16;      // 16-c slice within 64-c tile
    const float* __restrict__ in =
        P.feat[m] + (size_t)b * C_ * N_ + (size_t)(cblk * 64 + cb) * N_ + n;
    float f[16];
#pragma unroll
    for (int i = 0; i < 16; ++i) f[i] = in[(size_t)i * N_];
    half8 h0, h1;
#pragma unroll
    for (int j = 0; j < 8; ++j) { h0[j] = (_Float16)f[j]; h1[j] = (_Float16)f[8 + j]; }
    *(half8*)(lt + (tid & 63) * 72 + cb) = h0;
    *(half8*)(lt + (tid & 63) * 72 + cb + 8) = h1;
  }
  __syncthreads();
  {
    const int nr = tid >> 2, cs = (tid & 3) * 16;
    const half8 o0 = *(const half8*)(lt + nr * 72 + cs);
    const half8 o1 = *(const half8*)(lt + nr * 72 + cs + 8);
    _Float16* o = P.xT + ((size_t)(m * 2 + b) * N_ + nblk * 64 + nr) * C_ +
                  cblk * 64 + cs;
    *(half8*)o = o0;
    *(half8*)(o + 8) = o1;
  }
  if (b == 0 && blockIdx.x < 8) {
    const int s = blockIdx.x;
    const float* srcs[4] = {P.Wq[m], P.Wk[m], P.Wv[m], P.Wo[m]};
    _Float16* dsts[4] = {P.wq16[m], P.wk16[m], P.wv16[m], P.wo16[m]};
    const int sizes[4] = {64 * 256, 64 * 512, 64 * 512, 256 * 64};
#pragma unroll
    for (int a = 0; a < 4; ++a) {
      const int lo = sizes[a] / 8 * s, hi = sizes[a] / 8 * (s + 1);
      for (int i = lo + tid * 4; i < hi; i += 1024) {
        const float4 x = *(const float4*)(srcs[a] + i);
        half4 h; h[0] = (_Float16)x.x; h[1] = (_Float16)x.y;
        h[2] = (_Float16)x.z; h[3] = (_Float16)x.w;
        *(half4*)(dsts[a] + i) = h;
      }
    }
  }
  if (m == 0 && b == 0 && blockIdx.x == 8 && tid < 192) P.stats[tid] = 0.f;
}

// ---------------------------------------------------------------------------
// Fused Q + KV projection, 16x16x32 MFMA. Full-depth B-tile staging: ONE
// barrier pair per block (Q: 32n x 256c tile; KV: both src tiles, 33KB).
// LDS reused for the V transpose. grid (256, 2, 3): x<128 KV, x>=128 Q.
// ---------------------------------------------------------------------------
#define PBS_ 264  // padded row stride (halfs) for 256-c staged tiles

__global__ __launch_bounds__(256) void proj_qkv_kernel(TP P) {
  __shared__ _Float16 bs[2 * 32 * PBS_];  // 33,792 B (also V-transpose buf)
  const int m = blockIdx.z, b = blockIdx.y;
  const int tid = threadIdx.x;
  const int w = tid >> 6, g = (tid >> 4) & 3, t = tid & 15;
  const bool is_q = blockIdx.x >= 128;
  const int n0 = (is_q ? blockIdx.x - 128 : (int)blockIdx.x) * 32;
  const int sr = tid >> 3, sc = (tid & 7) * 32;  // staging coords

  if (is_q) {
    const _Float16* __restrict__ xb =
        P.xT + ((size_t)(m * 2 + b) * N_ + n0 + sr) * C_ + sc;
#pragma unroll
    for (int j = 0; j < 4; ++j)
      *(half8*)(bs + sr * PBS_ + sc + j * 8) = *(const half8*)(xb + j * 8);
    __syncthreads();
    f32x4 a0 = {0.f,0.f,0.f,0.f}, a1 = {0.f,0.f,0.f,0.f};
#pragma unroll
    for (int ks = 0; ks < 8; ++ks) {
      const half8 a = *(const half8*)(P.wq16[m] + (w * 16 + t) * 256 + ks * 32 + g * 8);
      const half8 b0 = *(const half8*)(bs + t * PBS_ + ks * 32 + g * 8);
      const half8 b1 = *(const half8*)(bs + (16 + t) * PBS_ + ks * 32 + g * 8);
      a0 = __builtin_amdgcn_mfma_f32_16x16x32_f16(a, b0, a0, 0, 0, 0);
      a1 = __builtin_amdgcn_mfma_f32_16x16x32_f16(a, b1, a1, 0, 0, 0);
    }
    _Float16* qo = P.q16 + ((size_t)(m * 2 + b) * N_) * 64 + w * 16 + g * 4;
    half4 h0, h1;
#pragma unroll
    for (int r = 0; r < 4; ++r) {
      const float bq = P.bq[m][w * 16 + g * 4 + r];
      h0[r] = (_Float16)((a0[r] + bq) * QSCALE_);
      h1[r] = (_Float16)((a1[r] + bq) * QSCALE_);
    }
    *(half4*)(qo + (size_t)(n0 + t) * 64) = h0;
    *(half4*)(qo + (size_t)(n0 + 16 + t) * 64) = h1;
  } else {
    const int srcs[2] = {P.ctx0[m], P.ctx1[m]};
#pragma unroll
    for (int src = 0; src < 2; ++src) {
      const _Float16* __restrict__ xb =
          P.xT + ((size_t)(srcs[src] * 2 + b) * N_ + n0 + sr) * C_ + sc;
#pragma unroll
      for (int j = 0; j < 4; ++j)
        *(half8*)(bs + src * 32 * PBS_ + sr * PBS_ + sc + j * 8) =
            *(const half8*)(xb + j * 8);
    }
    __syncthreads();
    f32x4 k0 = {0.f,0.f,0.f,0.f}, k1 = {0.f,0.f,0.f,0.f};
    f32x4 v0 = {0.f,0.f,0.f,0.f}, v1 = {0.f,0.f,0.f,0.f};
#pragma unroll
    for (int src = 0; src < 2; ++src) {
#pragma unroll
      for (int ks = 0; ks < 8; ++ks) {
        const half8 ak = *(const half8*)(P.wk16[m] + (w * 16 + t) * 512 +
                                         src * 256 + ks * 32 + g * 8);
        const half8 av = *(const half8*)(P.wv16[m] + (w * 16 + t) * 512 +
                                         src * 256 + ks * 32 + g * 8);
        const half8 b0 = *(const half8*)(bs + src * 32 * PBS_ + t * PBS_ + ks * 32 + g * 8);
        const half8 b1 = *(const half8*)(bs + src * 32 * PBS_ + (16 + t) * PBS_ + ks * 32 + g * 8);
        k0 = __builtin_amdgcn_mfma_f32_16x16x32_f16(ak, b0, k0, 0, 0, 0);
        k1 = __builtin_amdgcn_mfma_f32_16x16x32_f16(ak, b1, k1, 0, 0, 0);
        v0 = __builtin_amdgcn_mfma_f32_16x16x32_f16(av, b0, v0, 0, 0, 0);
        v1 = __builtin_amdgcn_mfma_f32_16x16x32_f16(av, b1, v1, 0, 0, 0);
      }
    }
    const int bh = m * 8 + b * 4 + w;
    _Float16* ko = P.k16 + ((size_t)bh * N_) * 16 + g * 4;
    half4 h0, h1;
#pragma unroll
    for (int r = 0; r < 4; ++r) {
      const float bk = P.bk[m][w * 16 + g * 4 + r];
      h0[r] = (_Float16)(k0[r] + bk);
      h1[r] = (_Float16)(k1[r] + bk);
    }
    *(half4*)(ko + (size_t)(n0 + t) * 16) = h0;
    *(half4*)(ko + (size_t)(n0 + 16 + t) * 16) = h1;
    // V: transpose through (reused) LDS, 16B coalesced global stores
    __syncthreads();
    _Float16* vt = bs;  // [head][d][n'(32)+pad8], stride 40
#pragma unroll
    for (int r = 0; r < 4; ++r) {
      const float bv = P.bv[m][w * 16 + g * 4 + r];
      vt[(w * 16 + g * 4 + r) * 40 + t] = (_Float16)(v0[r] + bv);
      vt[(w * 16 + g * 4 + r) * 40 + 16 + t] = (_Float16)(v1[r] + bv);
    }
    __syncthreads();
    const int hh = tid >> 6, dd = (tid >> 2) & 15, nb = (tid & 3) * 8;
    const half8 hv8 = *(const half8*)(vt + (hh * 16 + dd) * 40 + nb);
    *(half8*)(P.v16 + ((size_t)(m * 8 + b * 4 + hh) * 16 + dd) * N_ + n0 + nb) = hv8;
  }
}

// ---------------------------------------------------------------------------
// MFMA flash attention: R6 geometry (64 q/block, VGPR~40, occ~50%) + fast
// exp2. LDS-staged swizzled K/V chunks + register prefetch. Static softmax
// in exp2 domain. Writes ao f16 in place over q16 [n][64].
// grid (64, 8, 3), block 256 (wave = 16-q tile).
// ---------------------------------------------------------------------------
__global__ __launch_bounds__(256) void attn_kernel(TP P) {
  const int m = blockIdx.z, bh = blockIdx.y;
  const int tid = threadIdx.x;
  const int w = tid >> 6, g = (tid >> 4) & 3, t = tid & 15;
  const _Float16* __restrict__ kh = P.k16 + ((size_t)(m * 8 + bh) * N_) * 16;
  const _Float16* __restrict__ vh = P.v16 + ((size_t)(m * 8 + bh) * 16) * N_;
  const int b = bh >> 2, h = bh & 3;
  _Float16* qh = P.q16 + ((size_t)(m * 2 + b) * N_) * 64 + h * 16 + g * 4;

  const int q0 = blockIdx.x * 64 + w * 16;
  const half4 qf = *(const half4*)(qh + (size_t)(q0 + t) * 64);

  __shared__ _Float16 ks[128 * 16];  // [kv][d], 8-half blocks XOR-swizzled
  __shared__ _Float16 vs[16 * 128];  // [d][kv], 8-half blocks XOR-swizzled

  const int kr = tid >> 1, kc8 = tid & 1;
  const int vr = tid >> 4, vc = tid & 15;
  const _Float16* kgp = kh + (size_t)kr * 16 + kc8 * 8;
  const _Float16* vgp = vh + (size_t)vr * N_ + vc * 8;
  _Float16* ksp = ks + kr * 16 + ((kc8 ^ (kr & 1)) << 3);
  _Float16* vsp = vs + vr * 128 + ((vc ^ vr) << 3);

  half8 kpre = *(const half8*)kgp;
  half8 vpre = *(const half8*)vgp;

  f32x4 lacc = {0.f, 0.f, 0.f, 0.f};
  f32x4 O0 = {0.f,0.f,0.f,0.f}, O1 = {0.f,0.f,0.f,0.f};

  for (int kv0 = 0; kv0 < N_; kv0 += 128) {
    *(half8*)ksp = kpre;
    *(half8*)vsp = vpre;
    __syncthreads();
    const int nxt = (kv0 + 128 < N_) ? kv0 + 128 : 0;
    kpre = *(const half8*)(kgp + (size_t)nxt * 16);
    vpre = *(const half8*)(vgp + nxt);
#pragma unroll
    for (int hc = 0; hc < 2; ++hc) {
      f32x4 s[4];
#pragma unroll
      for (int i = 0; i < 4; ++i) {
        const int sub = hc * 4 + i;
        const half4 kf = *(const half4*)(ks + (sub * 16 + t) * 16 +
                          (((g >> 1) ^ (t & 1)) << 3) + (g & 1) * 4);
        const f32x4 z = {0.f, 0.f, 0.f, 0.f};
        s[i] = __builtin_amdgcn_mfma_f32_16x16x16f16(kf, qf, z, 0, 0, 0);
      }
      half4 pf[4];
#pragma unroll
      for (int i = 0; i < 4; ++i) {
        const float p0 = fexp2(s[i][0]), p1 = fexp2(s[i][1]);
        const float p2 = fexp2(s[i][2]), p3 = fexp2(s[i][3]);
        lacc[0] += p0; lacc[1] += p1; lacc[2] += p2; lacc[3] += p3;
        pf[i] = __builtin_shufflevector(pack2(p0, p1), pack2(p2, p3), 0, 1, 2, 3);
      }
#pragma unroll
      for (int i = 0; i < 4; ++i) {
        const int sub = hc * 4 + i;
        const half4 vf = *(const half4*)(vs + t * 128 +
                          (((sub * 2 + (g >> 1)) ^ t) << 3) + (g & 1) * 4);
        if (i & 1) O1 = __builtin_amdgcn_mfma_f32_16x16x16f16(vf, pf[i], O1, 0, 0, 0);
        else       O0 = __builtin_amdgcn_mfma_f32_16x16x16f16(vf, pf[i], O0, 0, 0, 0);
      }
    }
    __syncthreads();
  }
  float l = lacc[0] + lacc[1] + lacc[2] + lacc[3];
  l += __shfl_xor(l, 16);
  l += __shfl_xor(l, 32);
  const float inv = 1.0f / l;
  half4 hv;
#pragma unroll
  for (int r = 0; r < 4; ++r) hv[r] = (_Float16)((O0[r] + O1[r]) * inv);
  *(half4*)(qh + (size_t)(q0 + t) * 64) = hv;  // ao, in-place (lane-exact)
}

// ---------------------------------------------------------------------------
// Wo projection (16x16x32) + bias + residual -> d_out, fused GroupNorm
// stats. ao tile (64n x 64p) staged in LDS. grid (64, 8, 3).
// ---------------------------------------------------------------------------
#define BS_ 72

__global__ __launch_bounds__(256) void wo_resid_kernel(TP P) {
  __shared__ _Float16 as[64 * BS_];  // 9216 B
  const int m = blockIdx.z;
  const int b = blockIdx.y >> 2, cblk = blockIdx.y & 3;
  const int n0 = blockIdx.x * 64;
  const int tid = threadIdx.x;
  const int w = tid >> 6, g = (tid >> 4) & 3, t = tid & 15;
  const int c0 = cblk * 64 + w * 16;
  const _Float16* __restrict__ ao = P.q16 + ((size_t)(m * 2 + b) * N_) * 64;
  const int ar = tid >> 2, ac = (tid & 3) * 16;
  const half8 l0 = *(const half8*)(ao + (size_t)(n0 + ar) * 64 + ac);
  const half8 l1 = *(const half8*)(ao + (size_t)(n0 + ar) * 64 + ac + 8);
  *(half8*)(as + ar * BS_ + ac) = l0;
  *(half8*)(as + ar * BS_ + ac + 8) = l1;
  __syncthreads();
  f32x4 acc[4] = {{0.f,0.f,0.f,0.f},{0.f,0.f,0.f,0.f},{0.f,0.f,0.f,0.f},{0.f,0.f,0.f,0.f}};
#pragma unroll
  for (int kst = 0; kst < 2; ++kst) {
    const half8 a =
        *(const half8*)(P.wo16[m] + (c0 + t) * 64 + kst * 32 + g * 8);
#pragma unroll
    for (int i = 0; i < 4; ++i) {
      const half8 bf = *(const half8*)(as + (i * 16 + t) * BS_ + kst * 32 + g * 8);
      acc[i] = __builtin_amdgcn_mfma_f32_16x16x32_f16(a, bf, acc[i], 0, 0, 0);
    }
  }
  const float* __restrict__ X = P.feat[m] + (size_t)b * C_ * N_;
  float* outb = P.out + (size_t)m * B_ * C_ * N_ + (size_t)b * C_ * N_;
  float s = 0.f, s2 = 0.f;
#pragma unroll
  for (int i = 0; i < 4; ++i) {
    const int n = n0 + i * 16 + t;
#pragma unroll
    for (int r = 0; r < 4; ++r) {
      const int c = c0 + g * 4 + r;
      const float val = acc[i][r] + X[(size_t)c * N_ + n] + P.bo[m][c];
      outb[(size_t)c * N_ + n] = val;
      s += val;
      s2 += val * val;
    }
  }
#pragma unroll
  for (int off = 1; off < 64; off <<= 1) {
    s += __shfl_xor(s, off);
    s2 += __shfl_xor(s2, off);
  }
  if ((tid & 63) == 0) {
    const int group = cblk * 4 + w;
    float* st = P.stats + ((size_t)(m * 2 + b) * 16 + group) * 2;
    atomicAdd(st, s);
    atomicAdd(st + 1, s2);
  }
}

// ---------------------------------------------------------------------------
// GroupNorm normalize pass, 4 float4 per thread. grid (1536), block 256.
// ---------------------------------------------------------------------------
__global__ __launch_bounds__(256) void gn_final_kernel(TP P) {
  const size_t base = ((size_t)blockIdx.x * 256 + threadIdx.x) * 4;
#pragma unroll
  for (int it = 0; it < 4; ++it) {
    const size_t idx = base + (size_t)it * 1572864;
    const int m = (int)(idx >> 21);
    const int rem = (int)(idx & ((1u << 21) - 1));
    const int b = rem >> 20;
    const int c = (rem >> 12) & 255;
    const float* st = P.stats + ((size_t)(m * 2 + b) * 16 + (c >> 4)) * 2;
    const float mean = st[0] * (1.f / 65536.f);
    const float var = st[1] * (1.f / 65536.f) - mean * mean;
    const float rstd = rsqrtf(var + EPS_);
    const float ga = P.gm[m][c] * rstd, be = P.bt[m][c];
    float4 x = *(float4*)(P.out + idx);
    x.x = (x.x - mean) * ga + be;
    x.y = (x.y - mean) * ga + be;
    x.z = (x.z - mean) * ga + be;
    x.w = (x.w - mean) * ga + be;
    *(float4*)(P.out + idx) = x;
  }
}

// ---------------------------------------------------------------------------
extern "C" void kernel_launch(void* const* d_in, const int* in_sizes, int n_in,
                              void* d_out, int out_size, void* d_ws, size_t ws_size,
                              hipStream_t stream) {
  TP P;
  for (int m = 0; m < 3; ++m) {
    P.feat[m] = (const float*)d_in[m];
    const int base = 3 + m * 10;
    P.Wq[m] = (const float*)d_in[base + 0];
    P.bq[m] = (const float*)d_in[base + 1];
    P.Wk[m] = (const float*)d_in[base + 2];
    P.bk[m] = (const float*)d_in[base + 3];
    P.Wv[m] = (const float*)d_in[base + 4];
    P.bv[m] = (const float*)d_in[base + 5];
    P.Wo[m] = (const float*)d_in[base + 6];
    P.bo[m] = (const float*)d_in[base + 7];
    P.gm[m] = (const float*)d_in[base + 8];
    P.bt[m] = (const float*)d_in[base + 9];
  }
  _Float16* ws = (_Float16*)d_ws;
  P.xT = ws;                                    // 6,291,456 halfs
  P.q16 = ws + 6291456;                         // q / ao
  P.k16 = ws + 7864320;
  P.v16 = ws + 9437184;
  for (int m = 0; m < 3; ++m) {
    _Float16* wb = ws + 11010048 + (size_t)m * 98304;
    P.wq16[m] = wb;
    P.wk16[m] = wb + 16384;
    P.wv16[m] = wb + 49152;
    P.wo16[m] = wb + 81920;
  }
  P.stats = (float*)((char*)d_ws + 22609920);   // 192 floats
  P.out = (float*)d_out;
  P.ctx0[0] = 1; P.ctx1[0] = 2;
  P.ctx0[1] = 0; P.ctx1[1] = 2;
  P.ctx0[2] = 0; P.ctx1[2] = 1;

  dim3 blk(256);
  prep_kernel<<<dim3(256, 2, 3), blk, 0, stream>>>(P);
  proj_qkv_kernel<<<dim3(256, 2, 3), blk, 0, stream>>>(P);
  attn_kernel<<<dim3(64, 8, 3), blk, 0, stream>>>(P);
  wo_resid_kernel<<<dim3(64, 8, 3), blk, 0, stream>>>(P);
  gn_final_kernel<<<dim3(1536), blk, 0, stream>>>(P);
}

// Round 9
// 279.015 us; speedup vs baseline: 1.0096x; 1.0096x over previous
//
#include <hip/hip_runtime.h>

// Problem constants: B=2, C=256, P=64 (NH=4, HD=16), H=W=64 -> N=4096, G=16.
#define B_ 2
#define C_ 256
#define P_ 64
#define N_ 4096
#define EPS_ 1e-5f
// SCALE * log2(e): softmax computed in exp2 domain (folded into q)
#define QSCALE_ 0.3606737602222409f

typedef _Float16 half4 __attribute__((ext_vector_type(4)));
typedef _Float16 half8 __attribute__((ext_vector_type(8)));
typedef float f32x4 __attribute__((ext_vector_type(4)));

// Schraudolph fast exp2: 2 full-rate VALU ops vs quarter-rate v_exp_f32.
// Validated R8: absmax unchanged (softmax normalization cancels the bias).
static __device__ __forceinline__ float fexp2(float x) {
  return __builtin_bit_cast(float, (int)fmaf(x, 8388608.0f, 1064872512.0f));
}

struct TP {
  const float* feat[3];
  const float* Wq[3]; const float* bq[3];
  const float* Wk[3]; const float* bk[3];
  const float* Wv[3]; const float* bv[3];
  const float* Wo[3]; const float* bo[3];
  const float* gm[3]; const float* bt[3];
  _Float16* q16;   // [3][2][4096][64]  q (then ao, in place)
  _Float16* k16;   // [3][8(b4h)][4096][16]
  _Float16* v16;   // [3][8][16][4096]
  float* stats;    // [3][2][16][2] {sum, sumsq}
  float* out;
  int ctx0[3]; int ctx1[3];
};

// ---------------------------------------------------------------------------
// Fused projection (replaces prep + proj_qkv; no xT buffer). Each block
// stages a 64n x 256c fp32 feat tile -> LDS f16 [n][c] (prep's verified
// bank-pattern), W fragments converted fp32->f16 in registers (L2-hot).
// grid (128, 2, 3): x<64 -> KV block (K=512 over both ctx feats),
// x>=64 -> Q block. block 256 (wave w = head w, 4 n-subtiles).
// ---------------------------------------------------------------------------
#define PST_ 264  // feat-tile LDS row stride (halfs)
#define VTS_ 88   // V-transpose LDS row stride (halfs; 176B, 16B-aligned)

__global__ __launch_bounds__(256) void proj_fused_kernel(TP P) {
  __shared__ _Float16 bs[64 * PST_];  // 33,792 B (also V-transpose buffer)
  const int m = blockIdx.z, b = blockIdx.y;
  const int tid = threadIdx.x;
  const int w = tid >> 6, g = (tid >> 4) & 3, t = tid & 15;
  const bool is_q = blockIdx.x >= 64;
  const int n0 = (is_q ? blockIdx.x - 64 : (int)blockIdx.x) * 64;
  const int sn = tid & 63, scb = (tid >> 6) * 16;  // staging coords

  if (is_q) {
    const float* __restrict__ in = P.feat[m] + (size_t)b * C_ * N_ + n0 + sn;
#pragma unroll
    for (int cc = 0; cc < 4; ++cc) {
      const int c0 = cc * 64 + scb;
      float f[16];
#pragma unroll
      for (int i = 0; i < 16; ++i) f[i] = in[(size_t)(c0 + i) * N_];
      half8 h0, h1;
#pragma unroll
      for (int j = 0; j < 8; ++j) { h0[j] = (_Float16)f[j]; h1[j] = (_Float16)f[8 + j]; }
      *(half8*)(bs + sn * PST_ + c0) = h0;
      *(half8*)(bs + sn * PST_ + c0 + 8) = h1;
    }
    __syncthreads();
    f32x4 a[4] = {{0.f,0.f,0.f,0.f},{0.f,0.f,0.f,0.f},{0.f,0.f,0.f,0.f},{0.f,0.f,0.f,0.f}};
    const float* __restrict__ Wq = P.Wq[m] + (w * 16 + t) * 256;
#pragma unroll
    for (int ks = 0; ks < 8; ++ks) {
      const float4 wa = *(const float4*)(Wq + ks * 32 + g * 8);
      const float4 wb = *(const float4*)(Wq + ks * 32 + g * 8 + 4);
      half8 af;
      af[0] = (_Float16)wa.x; af[1] = (_Float16)wa.y;
      af[2] = (_Float16)wa.z; af[3] = (_Float16)wa.w;
      af[4] = (_Float16)wb.x; af[5] = (_Float16)wb.y;
      af[6] = (_Float16)wb.z; af[7] = (_Float16)wb.w;
#pragma unroll
      for (int i = 0; i < 4; ++i) {
        const half8 bf = *(const half8*)(bs + (i * 16 + t) * PST_ + ks * 32 + g * 8);
        a[i] = __builtin_amdgcn_mfma_f32_16x16x32_f16(af, bf, a[i], 0, 0, 0);
      }
    }
    float bq[4];
#pragma unroll
    for (int r = 0; r < 4; ++r) bq[r] = P.bq[m][w * 16 + g * 4 + r];
    _Float16* qo = P.q16 + ((size_t)(m * 2 + b) * N_) * 64 + w * 16 + g * 4;
#pragma unroll
    for (int i = 0; i < 4; ++i) {
      half4 hq;
#pragma unroll
      for (int r = 0; r < 4; ++r) hq[r] = (_Float16)((a[i][r] + bq[r]) * QSCALE_);
      *(half4*)(qo + (size_t)(n0 + i * 16 + t) * 64) = hq;
    }
  } else {
    f32x4 ka[4] = {{0.f,0.f,0.f,0.f},{0.f,0.f,0.f,0.f},{0.f,0.f,0.f,0.f},{0.f,0.f,0.f,0.f}};
    f32x4 va[4] = {{0.f,0.f,0.f,0.f},{0.f,0.f,0.f,0.f},{0.f,0.f,0.f,0.f},{0.f,0.f,0.f,0.f}};
    const int srcs[2] = {P.ctx0[m], P.ctx1[m]};
    for (int src = 0; src < 2; ++src) {
      const float* __restrict__ in =
          P.feat[srcs[src]] + (size_t)b * C_ * N_ + n0 + sn;
      if (src) __syncthreads();
#pragma unroll
      for (int cc = 0; cc < 4; ++cc) {
        const int c0 = cc * 64 + scb;
        float f[16];
#pragma unroll
        for (int i = 0; i < 16; ++i) f[i] = in[(size_t)(c0 + i) * N_];
        half8 h0, h1;
#pragma unroll
        for (int j = 0; j < 8; ++j) { h0[j] = (_Float16)f[j]; h1[j] = (_Float16)f[8 + j]; }
        *(half8*)(bs + sn * PST_ + c0) = h0;
        *(half8*)(bs + sn * PST_ + c0 + 8) = h1;
      }
      __syncthreads();
      const float* __restrict__ Wk = P.Wk[m] + (w * 16 + t) * 512 + src * 256;
      const float* __restrict__ Wv = P.Wv[m] + (w * 16 + t) * 512 + src * 256;
#pragma unroll
      for (int ks = 0; ks < 8; ++ks) {
        const float4 k0 = *(const float4*)(Wk + ks * 32 + g * 8);
        const float4 k1 = *(const float4*)(Wk + ks * 32 + g * 8 + 4);
        const float4 v0 = *(const float4*)(Wv + ks * 32 + g * 8);
        const float4 v1 = *(const float4*)(Wv + ks * 32 + g * 8 + 4);
        half8 ak, av;
        ak[0] = (_Float16)k0.x; ak[1] = (_Float16)k0.y;
        ak[2] = (_Float16)k0.z; ak[3] = (_Float16)k0.w;
        ak[4] = (_Float16)k1.x; ak[5] = (_Float16)k1.y;
        ak[6] = (_Float16)k1.z; ak[7] = (_Float16)k1.w;
        av[0] = (_Float16)v0.x; av[1] = (_Float16)v0.y;
        av[2] = (_Float16)v0.z; av[3] = (_Float16)v0.w;
        av[4] = (_Float16)v1.x; av[5] = (_Float16)v1.y;
        av[6] = (_Float16)v1.z; av[7] = (_Float16)v1.w;
#pragma unroll
        for (int i = 0; i < 4; ++i) {
          const half8 bf = *(const half8*)(bs + (i * 16 + t) * PST_ + ks * 32 + g * 8);
          ka[i] = __builtin_amdgcn_mfma_f32_16x16x32_f16(ak, bf, ka[i], 0, 0, 0);
          va[i] = __builtin_amdgcn_mfma_f32_16x16x32_f16(av, bf, va[i], 0, 0, 0);
        }
      }
    }
    float bk[4], bv[4];
#pragma unroll
    for (int r = 0; r < 4; ++r) {
      bk[r] = P.bk[m][w * 16 + g * 4 + r];
      bv[r] = P.bv[m][w * 16 + g * 4 + r];
    }
    _Float16* ko = P.k16 + ((size_t)(m * 8 + b * 4 + w) * N_) * 16 + g * 4;
#pragma unroll
    for (int i = 0; i < 4; ++i) {
      half4 hk;
#pragma unroll
      for (int r = 0; r < 4; ++r) hk[r] = (_Float16)(ka[i][r] + bk[r]);
      *(half4*)(ko + (size_t)(n0 + i * 16 + t) * 16) = hk;
    }
    // V: transpose through (reused) LDS, then 128B-coalesced global stores
    __syncthreads();
#pragma unroll
    for (int i = 0; i < 4; ++i)
#pragma unroll
      for (int r = 0; r < 4; ++r)
        bs[(w * 16 + g * 4 + r) * VTS_ + i * 16 + t] = (_Float16)(va[i][r] + bv[r]);
    __syncthreads();
#pragma unroll
    for (int pass = 0; pass < 2; ++pass) {
      const int row = pass * 32 + (tid >> 3);     // 0..63 = head*16 + d
      const int hh = row >> 4, dd = row & 15, nb = (tid & 7) * 8;
      const half8 hv = *(const half8*)(bs + row * VTS_ + nb);
      *(half8*)(P.v16 + ((size_t)(m * 8 + b * 4 + hh) * 16 + dd) * N_ + n0 + nb) = hv;
    }
  }
}

// ---------------------------------------------------------------------------
// MFMA flash attention: 512-thread blocks (8 waves), 128 q/block (wave =
// one 16-q tile -> R6 per-wave register footprint), 256-kv LDS chunks
// (swizzled, conflict-floor), register prefetch, Schraudolph exp2 static
// softmax. Writes ao f16 in place over q16 [n][64]. grid (32, 8, 3).
// ---------------------------------------------------------------------------
__global__ __launch_bounds__(512) void attn_kernel(TP P) {
  const int m = blockIdx.z, bh = blockIdx.y;
  const int tid = threadIdx.x;
  if (m == 0 && bh == 0 && blockIdx.x == 0 && tid < 192) P.stats[tid] = 0.f;
  const int w = tid >> 6, g = (tid >> 4) & 3, t = tid & 15;
  const _Float16* __restrict__ kh = P.k16 + ((size_t)(m * 8 + bh) * N_) * 16;
  const _Float16* __restrict__ vh = P.v16 + ((size_t)(m * 8 + bh) * 16) * N_;
  const int b = bh >> 2, h = bh & 3;
  _Float16* qh = P.q16 + ((size_t)(m * 2 + b) * N_) * 64 + h * 16 + g * 4;

  const int q0 = blockIdx.x * 128 + w * 16;
  const half4 qf = *(const half4*)(qh + (size_t)(q0 + t) * 64);

  __shared__ _Float16 ks[256 * 16];  // [kv][d], 8-half blocks XOR-swizzled
  __shared__ _Float16 vs[16 * 256];  // [d][kv], 8-half blocks XOR-swizzled

  const int kr = tid >> 1, kc8 = tid & 1;   // K: 256 rows x 2 half8
  const int vr = tid >> 5, vc = tid & 31;   // V: 16 rows x 32 half8
  const _Float16* kgp = kh + (size_t)kr * 16 + kc8 * 8;
  const _Float16* vgp = vh + (size_t)vr * N_ + vc * 8;
  _Float16* ksp = ks + kr * 16 + ((kc8 ^ (kr & 1)) << 3);
  _Float16* vsp = vs + vr * 256 + ((vc ^ vr) << 3);

  half8 kpre = *(const half8*)kgp;
  half8 vpre = *(const half8*)vgp;

  f32x4 lacc = {0.f, 0.f, 0.f, 0.f};
  f32x4 O0 = {0.f,0.f,0.f,0.f}, O1 = {0.f,0.f,0.f,0.f};

  for (int kv0 = 0; kv0 < N_; kv0 += 256) {
    *(half8*)ksp = kpre;
    *(half8*)vsp = vpre;
    __syncthreads();
    const int nxt = (kv0 + 256 < N_) ? kv0 + 256 : 0;
    kpre = *(const half8*)(kgp + (size_t)nxt * 16);
    vpre = *(const half8*)(vgp + nxt);
#pragma unroll
    for (int hc = 0; hc < 4; ++hc) {
      f32x4 s[4];
#pragma unroll
      for (int i = 0; i < 4; ++i) {
        const int sub = hc * 4 + i;
        const half4 kf = *(const half4*)(ks + (sub * 16 + t) * 16 +
                          (((g >> 1) ^ (t & 1)) << 3) + (g & 1) * 4);
        const f32x4 z = {0.f, 0.f, 0.f, 0.f};
        s[i] = __builtin_amdgcn_mfma_f32_16x16x16f16(kf, qf, z, 0, 0, 0);
      }
      half4 pf[4];
#pragma unroll
      for (int i = 0; i < 4; ++i) {
        const float p0 = fexp2(s[i][0]), p1 = fexp2(s[i][1]);
        const float p2 = fexp2(s[i][2]), p3 = fexp2(s[i][3]);
        lacc[0] += p0; lacc[1] += p1; lacc[2] += p2; lacc[3] += p3;
        pf[i][0] = (_Float16)p0; pf[i][1] = (_Float16)p1;
        pf[i][2] = (_Float16)p2; pf[i][3] = (_Float16)p3;
      }
#pragma unroll
      for (int i = 0; i < 4; ++i) {
        const int c = (hc * 4 + i) * 2 + (g >> 1);
        const half4 vf = *(const half4*)(vs + t * 256 + ((c ^ t) << 3) + (g & 1) * 4);
        if (i & 1) O1 = __builtin_amdgcn_mfma_f32_16x16x16f16(vf, pf[i], O1, 0, 0, 0);
        else       O0 = __builtin_amdgcn_mfma_f32_16x16x16f16(vf, pf[i], O0, 0, 0, 0);
      }
    }
    __syncthreads();
  }
  float l = lacc[0] + lacc[1] + lacc[2] + lacc[3];
  l += __shfl_xor(l, 16);
  l += __shfl_xor(l, 32);
  const float inv = 1.0f / l;
  half4 hv;
#pragma unroll
  for (int r = 0; r < 4; ++r) hv[r] = (_Float16)((O0[r] + O1[r]) * inv);
  *(half4*)(qh + (size_t)(q0 + t) * 64) = hv;  // ao, in-place (lane-exact)
}

// ---------------------------------------------------------------------------
// Wo projection (16x16x32, Wo fp32->f16 in-register) + bias + residual ->
// d_out, fused GroupNorm stats (wave = one group). grid (64, 8, 3).
// ---------------------------------------------------------------------------
#define BS_ 72

__global__ __launch_bounds__(256) void wo_resid_kernel(TP P) {
  __shared__ _Float16 as[64 * BS_];  // 9216 B
  const int m = blockIdx.z;
  const int b = blockIdx.y >> 2, cblk = blockIdx.y & 3;
  const int n0 = blockIdx.x * 64;
  const int tid = threadIdx.x;
  const int w = tid >> 6, g = (tid >> 4) & 3, t = tid & 15;
  const int c0 = cblk * 64 + w * 16;
  const _Float16* __restrict__ ao = P.q16 + ((size_t)(m * 2 + b) * N_) * 64;
  const int ar = tid >> 2, ac = (tid & 3) * 16;
  const half8 l0 = *(const half8*)(ao + (size_t)(n0 + ar) * 64 + ac);
  const half8 l1 = *(const half8*)(ao + (size_t)(n0 + ar) * 64 + ac + 8);
  *(half8*)(as + ar * BS_ + ac) = l0;
  *(half8*)(as + ar * BS_ + ac + 8) = l1;
  __syncthreads();
  f32x4 acc[4] = {{0.f,0.f,0.f,0.f},{0.f,0.f,0.f,0.f},{0.f,0.f,0.f,0.f},{0.f,0.f,0.f,0.f}};
  const float* __restrict__ Wo = P.Wo[m] + (c0 + t) * 64;
#pragma unroll
  for (int kst = 0; kst < 2; ++kst) {
    const float4 w0 = *(const float4*)(Wo + kst * 32 + g * 8);
    const float4 w1 = *(const float4*)(Wo + kst * 32 + g * 8 + 4);
    half8 a;
    a[0] = (_Float16)w0.x; a[1] = (_Float16)w0.y;
    a[2] = (_Float16)w0.z; a[3] = (_Float16)w0.w;
    a[4] = (_Float16)w1.x; a[5] = (_Float16)w1.y;
    a[6] = (_Float16)w1.z; a[7] = (_Float16)w1.w;
#pragma unroll
    for (int i = 0; i < 4; ++i) {
      const half8 bf = *(const half8*)(as + (i * 16 + t) * BS_ + kst * 32 + g * 8);
      acc[i] = __builtin_amdgcn_mfma_f32_16x16x32_f16(a, bf, acc[i], 0, 0, 0);
    }
  }
  const float* __restrict__ X = P.feat[m] + (size_t)b * C_ * N_;
  float* outb = P.out + (size_t)m * B_ * C_ * N_ + (size_t)b * C_ * N_;
  float s = 0.f, s2 = 0.f;
#pragma unroll
  for (int i = 0; i < 4; ++i) {
    const int n = n0 + i * 16 + t;
#pragma unroll
    for (int r = 0; r < 4; ++r) {
      const int c = c0 + g * 4 + r;
      const float val = acc[i][r] + X[(size_t)c * N_ + n] + P.bo[m][c];
      outb[(size_t)c * N_ + n] = val;
      s += val;
      s2 += val * val;
    }
  }
#pragma unroll
  for (int off = 1; off < 64; off <<= 1) {
    s += __shfl_xor(s, off);
    s2 += __shfl_xor(s2, off);
  }
  if ((tid & 63) == 0) {
    const int group = cblk * 4 + w;
    float* st = P.stats + ((size_t)(m * 2 + b) * 16 + group) * 2;
    atomicAdd(st, s);
    atomicAdd(st + 1, s2);
  }
}

// ---------------------------------------------------------------------------
// GroupNorm normalize pass, 4 float4 per thread. grid (1536), block 256.
// ---------------------------------------------------------------------------
__global__ __launch_bounds__(256) void gn_final_kernel(TP P) {
  const size_t base = ((size_t)blockIdx.x * 256 + threadIdx.x) * 4;
#pragma unroll
  for (int it = 0; it < 4; ++it) {
    const size_t idx = base + (size_t)it * 1572864;
    const int m = (int)(idx >> 21);
    const int rem = (int)(idx & ((1u << 21) - 1));
    const int b = rem >> 20;
    const int c = (rem >> 12) & 255;
    const float* st = P.stats + ((size_t)(m * 2 + b) * 16 + (c >> 4)) * 2;
    const float mean = st[0] * (1.f / 65536.f);
    const float var = st[1] * (1.f / 65536.f) - mean * mean;
    const float rstd = rsqrtf(var + EPS_);
    const float ga = P.gm[m][c] * rstd, be = P.bt[m][c];
    float4 x = *(float4*)(P.out + idx);
    x.x = (x.x - mean) * ga + be;
    x.y = (x.y - mean) * ga + be;
    x.z = (x.z - mean) * ga + be;
    x.w = (x.w - mean) * ga + be;
    *(float4*)(P.out + idx) = x;
  }
}

// ---------------------------------------------------------------------------
extern "C" void kernel_launch(void* const* d_in, const int* in_sizes, int n_in,
                              void* d_out, int out_size, void* d_ws, size_t ws_size,
                              hipStream_t stream) {
  TP P;
  for (int m = 0; m < 3; ++m) {
    P.feat[m] = (const float*)d_in[m];
    const int base = 3 + m * 10;
    P.Wq[m] = (const float*)d_in[base + 0];
    P.bq[m] = (const float*)d_in[base + 1];
    P.Wk[m] = (const float*)d_in[base + 2];
    P.bk[m] = (const float*)d_in[base + 3];
    P.Wv[m] = (const float*)d_in[base + 4];
    P.bv[m] = (const float*)d_in[base + 5];
    P.Wo[m] = (const float*)d_in[base + 6];
    P.bo[m] = (const float*)d_in[base + 7];
    P.gm[m] = (const float*)d_in[base + 8];
    P.bt[m] = (const float*)d_in[base + 9];
  }
  _Float16* ws = (_Float16*)d_ws;
  P.q16 = ws;                   // 1,572,864 halfs (q -> ao in place)
  P.k16 = ws + 1572864;
  P.v16 = ws + 3145728;
  P.stats = (float*)(ws + 4718592);  // 192 floats
  P.out = (float*)d_out;
  P.ctx0[0] = 1; P.ctx1[0] = 2;
  P.ctx0[1] = 0; P.ctx1[1] = 2;
  P.ctx0[2] = 0; P.ctx1[2] = 1;

  proj_fused_kernel<<<dim3(128, 2, 3), dim3(256), 0, stream>>>(P);
  attn_kernel<<<dim3(32, 8, 3), dim3(512), 0, stream>>>(P);
  wo_resid_kernel<<<dim3(64, 8, 3), dim3(256), 0, stream>>>(P);
  gn_final_kernel<<<dim3(1536), dim3(256), 0, stream>>>(P);
}

// Round 10
// 273.181 us; speedup vs baseline: 1.0312x; 1.0214x over previous
//
#include <hip/hip_runtime.h>

// Problem constants: B=2, C=256, P=64 (NH=4, HD=16), H=W=64 -> N=4096, G=16.
#define B_ 2
#define C_ 256
#define P_ 64
#define N_ 4096
#define EPS_ 1e-5f
// SCALE * log2(e): softmax computed in exp2 domain (folded into q)
#define QSCALE_ 0.3606737602222409f

typedef _Float16 half4 __attribute__((ext_vector_type(4)));
typedef _Float16 half8 __attribute__((ext_vector_type(8)));
typedef float f32x4 __attribute__((ext_vector_type(4)));

// Schraudolph fast exp2 (validated R8/R9: absmax unchanged).
static __device__ __forceinline__ float fexp2(float x) {
  return __builtin_bit_cast(float, (int)fmaf(x, 8388608.0f, 1064872512.0f));
}

struct TP {
  const float* feat[3];
  const float* Wq[3]; const float* bq[3];
  const float* Wk[3]; const float* bk[3];
  const float* Wv[3]; const float* bv[3];
  const float* Wo[3]; const float* bo[3];
  const float* gm[3]; const float* bt[3];
  _Float16* q16;   // [3][2][4096][64]  scaled q
  _Float16* k16;   // [3][8(b4h)][4096][16]
  _Float16* v16;   // [3][8][16][4096]
  _Float16* ao0;   // [3][2][4096][64]  unnormalized O, kv-half 0
  _Float16* ao1;   // kv-half 1
  float* L;        // [2][3][8(bh)][4096] softmax partial denominators
  float* stats;    // [3][2][16][2] {sum, sumsq}
  float* out;
  int ctx0[3]; int ctx1[3];
};

// ---------------------------------------------------------------------------
// Fused projection (unchanged from R9): stages 64n x 256c fp32 feat tile ->
// LDS f16 [n][c]; W fragments converted fp32->f16 in registers.
// grid (128, 2, 3): x<64 KV (K=512 both ctx feats), x>=64 Q. block 256.
// ---------------------------------------------------------------------------
#define PST_ 264
#define VTS_ 88

__global__ __launch_bounds__(256) void proj_fused_kernel(TP P) {
  __shared__ _Float16 bs[64 * PST_];
  const int m = blockIdx.z, b = blockIdx.y;
  const int tid = threadIdx.x;
  const int w = tid >> 6, g = (tid >> 4) & 3, t = tid & 15;
  const bool is_q = blockIdx.x >= 64;
  const int n0 = (is_q ? blockIdx.x - 64 : (int)blockIdx.x) * 64;
  const int sn = tid & 63, scb = (tid >> 6) * 16;

  if (is_q) {
    const float* __restrict__ in = P.feat[m] + (size_t)b * C_ * N_ + n0 + sn;
#pragma unroll
    for (int cc = 0; cc < 4; ++cc) {
      const int c0 = cc * 64 + scb;
      float f[16];
#pragma unroll
      for (int i = 0; i < 16; ++i) f[i] = in[(size_t)(c0 + i) * N_];
      half8 h0, h1;
#pragma unroll
      for (int j = 0; j < 8; ++j) { h0[j] = (_Float16)f[j]; h1[j] = (_Float16)f[8 + j]; }
      *(half8*)(bs + sn * PST_ + c0) = h0;
      *(half8*)(bs + sn * PST_ + c0 + 8) = h1;
    }
    __syncthreads();
    f32x4 a[4] = {{0.f,0.f,0.f,0.f},{0.f,0.f,0.f,0.f},{0.f,0.f,0.f,0.f},{0.f,0.f,0.f,0.f}};
    const float* __restrict__ Wq = P.Wq[m] + (w * 16 + t) * 256;
#pragma unroll
    for (int ks = 0; ks < 8; ++ks) {
      const float4 wa = *(const float4*)(Wq + ks * 32 + g * 8);
      const float4 wb = *(const float4*)(Wq + ks * 32 + g * 8 + 4);
      half8 af;
      af[0] = (_Float16)wa.x; af[1] = (_Float16)wa.y;
      af[2] = (_Float16)wa.z; af[3] = (_Float16)wa.w;
      af[4] = (_Float16)wb.x; af[5] = (_Float16)wb.y;
      af[6] = (_Float16)wb.z; af[7] = (_Float16)wb.w;
#pragma unroll
      for (int i = 0; i < 4; ++i) {
        const half8 bf = *(const half8*)(bs + (i * 16 + t) * PST_ + ks * 32 + g * 8);
        a[i] = __builtin_amdgcn_mfma_f32_16x16x32_f16(af, bf, a[i], 0, 0, 0);
      }
    }
    float bq[4];
#pragma unroll
    for (int r = 0; r < 4; ++r) bq[r] = P.bq[m][w * 16 + g * 4 + r];
    _Float16* qo = P.q16 + ((size_t)(m * 2 + b) * N_) * 64 + w * 16 + g * 4;
#pragma unroll
    for (int i = 0; i < 4; ++i) {
      half4 hq;
#pragma unroll
      for (int r = 0; r < 4; ++r) hq[r] = (_Float16)((a[i][r] + bq[r]) * QSCALE_);
      *(half4*)(qo + (size_t)(n0 + i * 16 + t) * 64) = hq;
    }
  } else {
    f32x4 ka[4] = {{0.f,0.f,0.f,0.f},{0.f,0.f,0.f,0.f},{0.f,0.f,0.f,0.f},{0.f,0.f,0.f,0.f}};
    f32x4 va[4] = {{0.f,0.f,0.f,0.f},{0.f,0.f,0.f,0.f},{0.f,0.f,0.f,0.f},{0.f,0.f,0.f,0.f}};
    const int srcs[2] = {P.ctx0[m], P.ctx1[m]};
    for (int src = 0; src < 2; ++src) {
      const float* __restrict__ in =
          P.feat[srcs[src]] + (size_t)b * C_ * N_ + n0 + sn;
      if (src) __syncthreads();
#pragma unroll
      for (int cc = 0; cc < 4; ++cc) {
        const int c0 = cc * 64 + scb;
        float f[16];
#pragma unroll
        for (int i = 0; i < 16; ++i) f[i] = in[(size_t)(c0 + i) * N_];
        half8 h0, h1;
#pragma unroll
        for (int j = 0; j < 8; ++j) { h0[j] = (_Float16)f[j]; h1[j] = (_Float16)f[8 + j]; }
        *(half8*)(bs + sn * PST_ + c0) = h0;
        *(half8*)(bs + sn * PST_ + c0 + 8) = h1;
      }
      __syncthreads();
      const float* __restrict__ Wk = P.Wk[m] + (w * 16 + t) * 512 + src * 256;
      const float* __restrict__ Wv = P.Wv[m] + (w * 16 + t) * 512 + src * 256;
#pragma unroll
      for (int ks = 0; ks < 8; ++ks) {
        const float4 k0 = *(const float4*)(Wk + ks * 32 + g * 8);
        const float4 k1 = *(const float4*)(Wk + ks * 32 + g * 8 + 4);
        const float4 v0 = *(const float4*)(Wv + ks * 32 + g * 8);
        const float4 v1 = *(const float4*)(Wv + ks * 32 + g * 8 + 4);
        half8 ak, av;
        ak[0] = (_Float16)k0.x; ak[1] = (_Float16)k0.y;
        ak[2] = (_Float16)k0.z; ak[3] = (_Float16)k0.w;
        ak[4] = (_Float16)k1.x; ak[5] = (_Float16)k1.y;
        ak[6] = (_Float16)k1.z; ak[7] = (_Float16)k1.w;
        av[0] = (_Float16)v0.x; av[1] = (_Float16)v0.y;
        av[2] = (_Float16)v0.z; av[3] = (_Float16)v0.w;
        av[4] = (_Float16)v1.x; av[5] = (_Float16)v1.y;
        av[6] = (_Float16)v1.z; av[7] = (_Float16)v1.w;
#pragma unroll
        for (int i = 0; i < 4; ++i) {
          const half8 bf = *(const half8*)(bs + (i * 16 + t) * PST_ + ks * 32 + g * 8);
          ka[i] = __builtin_amdgcn_mfma_f32_16x16x32_f16(ak, bf, ka[i], 0, 0, 0);
          va[i] = __builtin_amdgcn_mfma_f32_16x16x32_f16(av, bf, va[i], 0, 0, 0);
        }
      }
    }
    float bk[4], bv[4];
#pragma unroll
    for (int r = 0; r < 4; ++r) {
      bk[r] = P.bk[m][w * 16 + g * 4 + r];
      bv[r] = P.bv[m][w * 16 + g * 4 + r];
    }
    _Float16* ko = P.k16 + ((size_t)(m * 8 + b * 4 + w) * N_) * 16 + g * 4;
#pragma unroll
    for (int i = 0; i < 4; ++i) {
      half4 hk;
#pragma unroll
      for (int r = 0; r < 4; ++r) hk[r] = (_Float16)(ka[i][r] + bk[r]);
      *(half4*)(ko + (size_t)(n0 + i * 16 + t) * 16) = hk;
    }
    __syncthreads();
#pragma unroll
    for (int i = 0; i < 4; ++i)
#pragma unroll
      for (int r = 0; r < 4; ++r)
        bs[(w * 16 + g * 4 + r) * VTS_ + i * 16 + t] = (_Float16)(va[i][r] + bv[r]);
    __syncthreads();
#pragma unroll
    for (int pass = 0; pass < 2; ++pass) {
      const int row = pass * 32 + (tid >> 3);
      const int hh = row >> 4, dd = row & 15, nb = (tid & 7) * 8;
      const half8 hv = *(const half8*)(bs + row * VTS_ + nb);
      *(half8*)(P.v16 + ((size_t)(m * 8 + b * 4 + hh) * 16 + dd) * N_ + n0 + nb) = hv;
    }
  }
}

// ---------------------------------------------------------------------------
// MFMA flash attention, split-kv x2. 512-thread blocks (8 waves, wave = one
// 16-q tile); each block covers 128 q x 2048 kv. ks stride 24 halfs: K
// fragment reads are provably at the LDS bank-volume floor (zero conflicts);
// vs keeps the validated XOR scheme. Static softmax partials: writes
// UNNORMALIZED O (f16) to ao0/ao1 and partial l (f32) to L; wo combines.
// grid (64, 8, 3): x = qb*2 + kv-half.
// ---------------------------------------------------------------------------
#define KST_ 24

__global__ __launch_bounds__(512) void attn_kernel(TP P) {
  const int m = blockIdx.z, bh = blockIdx.y;
  const int tid = threadIdx.x;
  if (m == 0 && bh == 0 && blockIdx.x == 0 && tid < 192) P.stats[tid] = 0.f;
  const int kvh = blockIdx.x & 1, qb = blockIdx.x >> 1;
  const int kvbase = kvh * 2048;
  const int w = tid >> 6, g = (tid >> 4) & 3, t = tid & 15;
  const _Float16* __restrict__ kh = P.k16 + ((size_t)(m * 8 + bh) * N_) * 16;
  const _Float16* __restrict__ vh = P.v16 + ((size_t)(m * 8 + bh) * 16) * N_;
  const int b = bh >> 2, h = bh & 3;
  const _Float16* __restrict__ qh =
      P.q16 + ((size_t)(m * 2 + b) * N_) * 64 + h * 16 + g * 4;

  const int q0 = qb * 128 + w * 16;
  const half4 qf = *(const half4*)(qh + (size_t)(q0 + t) * 64);

  __shared__ _Float16 ks[256 * KST_];  // [kv][d] stride 24 -> floor banks
  __shared__ _Float16 vs[16 * 256];    // [d][kv], XOR-swizzled (floor)

  const int kr = tid >> 1, kc8 = tid & 1;   // K: 256 rows x 2 half8
  const int vr = tid >> 5, vc = tid & 31;   // V: 16 rows x 32 half8
  const _Float16* kgp = kh + (size_t)(kvbase + kr) * 16 + kc8 * 8;
  const _Float16* vgp = vh + (size_t)vr * N_ + kvbase + vc * 8;
  _Float16* ksp = ks + kr * KST_ + kc8 * 8;
  _Float16* vsp = vs + vr * 256 + ((vc ^ vr) << 3);

  half8 kpre = *(const half8*)kgp;
  half8 vpre = *(const half8*)vgp;

  f32x4 lacc = {0.f, 0.f, 0.f, 0.f};
  f32x4 O0 = {0.f,0.f,0.f,0.f}, O1 = {0.f,0.f,0.f,0.f};

  for (int c0 = 0; c0 < 2048; c0 += 256) {
    *(half8*)ksp = kpre;
    *(half8*)vsp = vpre;
    __syncthreads();
    const int nxt = (c0 + 256 < 2048) ? c0 + 256 : 0;
    kpre = *(const half8*)(kgp + (size_t)nxt * 16);
    vpre = *(const half8*)(vgp + nxt);
#pragma unroll
    for (int hc = 0; hc < 4; ++hc) {
      f32x4 s[4];
#pragma unroll
      for (int i = 0; i < 4; ++i) {
        const int sub = hc * 4 + i;
        const half4 kf = *(const half4*)(ks + (sub * 16 + t) * KST_ +
                                         (g >> 1) * 8 + (g & 1) * 4);
        const f32x4 z = {0.f, 0.f, 0.f, 0.f};
        s[i] = __builtin_amdgcn_mfma_f32_16x16x16f16(kf, qf, z, 0, 0, 0);
      }
      half4 pf[4];
#pragma unroll
      for (int i = 0; i < 4; ++i) {
        const float p0 = fexp2(s[i][0]), p1 = fexp2(s[i][1]);
        const float p2 = fexp2(s[i][2]), p3 = fexp2(s[i][3]);
        lacc[0] += p0; lacc[1] += p1; lacc[2] += p2; lacc[3] += p3;
        pf[i][0] = (_Float16)p0; pf[i][1] = (_Float16)p1;
        pf[i][2] = (_Float16)p2; pf[i][3] = (_Float16)p3;
      }
#pragma unroll
      for (int i = 0; i < 4; ++i) {
        const int c = (hc * 4 + i) * 2 + (g >> 1);
        const half4 vf = *(const half4*)(vs + t * 256 + ((c ^ t) << 3) + (g & 1) * 4);
        if (i & 1) O1 = __builtin_amdgcn_mfma_f32_16x16x16f16(vf, pf[i], O1, 0, 0, 0);
        else       O0 = __builtin_amdgcn_mfma_f32_16x16x16f16(vf, pf[i], O0, 0, 0, 0);
      }
    }
    __syncthreads();
  }
  float l = lacc[0] + lacc[1] + lacc[2] + lacc[3];
  l += __shfl_xor(l, 16);
  l += __shfl_xor(l, 32);
  _Float16* aop = (kvh ? P.ao1 : P.ao0) +
                  ((size_t)(m * 2 + b) * N_ + q0 + t) * 64 + h * 16 + g * 4;
  half4 hv;
#pragma unroll
  for (int r = 0; r < 4; ++r) hv[r] = (_Float16)(O0[r] + O1[r]);  // UNNORMALIZED
  *(half4*)aop = hv;
  if (g == 0 && (tid & 48) == 0)
    P.L[((size_t)(kvh * 3 + m) * 8 + bh) * N_ + q0 + t] = l;
}

// ---------------------------------------------------------------------------
// Wo projection + bias + residual -> d_out, fused GroupNorm stats.
// Stages ao0+ao1 (summed) in LDS; per-fragment lane-uniform 1/(l0+l1) scale
// applied pre-MFMA (head = kst*2 + (g>>1) is fragment-uniform).
// grid (64, 8, 3).
// ---------------------------------------------------------------------------
#define BS_ 72

__global__ __launch_bounds__(256) void wo_resid_kernel(TP P) {
  __shared__ _Float16 as[64 * BS_];
  const int m = blockIdx.z;
  const int b = blockIdx.y >> 2, cblk = blockIdx.y & 3;
  const int n0 = blockIdx.x * 64;
  const int tid = threadIdx.x;
  const int w = tid >> 6, g = (tid >> 4) & 3, t = tid & 15;
  const int c0 = cblk * 64 + w * 16;
  const size_t aob = ((size_t)(m * 2 + b) * N_) * 64;
  const _Float16* __restrict__ a0p = P.ao0 + aob;
  const _Float16* __restrict__ a1p = P.ao1 + aob;
  // stage summed ao tile
  const int ar = tid >> 2, ac = (tid & 3) * 16;
  {
    const size_t off = (size_t)(n0 + ar) * 64 + ac;
    half8 s0 = *(const half8*)(a0p + off);
    half8 s1 = *(const half8*)(a0p + off + 8);
    const half8 u0 = *(const half8*)(a1p + off);
    const half8 u1 = *(const half8*)(a1p + off + 8);
#pragma unroll
    for (int r = 0; r < 8; ++r) { s0[r] += u0[r]; s1[r] += u1[r]; }
    *(half8*)(as + ar * BS_ + ac) = s0;
    *(half8*)(as + ar * BS_ + ac + 8) = s1;
  }
  __syncthreads();
  const float* __restrict__ L0 = P.L + ((size_t)m * 8 + b * 4) * N_;
  const float* __restrict__ L1 = P.L + ((size_t)(3 + m) * 8 + b * 4) * N_;
  f32x4 acc[4] = {{0.f,0.f,0.f,0.f},{0.f,0.f,0.f,0.f},{0.f,0.f,0.f,0.f},{0.f,0.f,0.f,0.f}};
  const float* __restrict__ Wo = P.Wo[m] + (c0 + t) * 64;
#pragma unroll
  for (int kst = 0; kst < 2; ++kst) {
    const float4 w0 = *(const float4*)(Wo + kst * 32 + g * 8);
    const float4 w1 = *(const float4*)(Wo + kst * 32 + g * 8 + 4);
    half8 a;
    a[0] = (_Float16)w0.x; a[1] = (_Float16)w0.y;
    a[2] = (_Float16)w0.z; a[3] = (_Float16)w0.w;
    a[4] = (_Float16)w1.x; a[5] = (_Float16)w1.y;
    a[6] = (_Float16)w1.z; a[7] = (_Float16)w1.w;
    const int head = kst * 2 + (g >> 1);
#pragma unroll
    for (int i = 0; i < 4; ++i) {
      const int n = n0 + i * 16 + t;
      half8 bf = *(const half8*)(as + (i * 16 + t) * BS_ + kst * 32 + g * 8);
      const float ls = L0[(size_t)head * N_ + n] + L1[(size_t)head * N_ + n];
      const _Float16 hs = (_Float16)(1.0f / ls);
#pragma unroll
      for (int r = 0; r < 8; ++r) bf[r] *= hs;
      acc[i] = __builtin_amdgcn_mfma_f32_16x16x32_f16(a, bf, acc[i], 0, 0, 0);
    }
  }
  const float* __restrict__ X = P.feat[m] + (size_t)b * C_ * N_;
  float* outb = P.out + (size_t)m * B_ * C_ * N_ + (size_t)b * C_ * N_;
  float s = 0.f, s2 = 0.f;
#pragma unroll
  for (int i = 0; i < 4; ++i) {
    const int n = n0 + i * 16 + t;
#pragma unroll
    for (int r = 0; r < 4; ++r) {
      const int c = c0 + g * 4 + r;
      const float val = acc[i][r] + X[(size_t)c * N_ + n] + P.bo[m][c];
      outb[(size_t)c * N_ + n] = val;
      s += val;
      s2 += val * val;
    }
  }
#pragma unroll
  for (int off = 1; off < 64; off <<= 1) {
    s += __shfl_xor(s, off);
    s2 += __shfl_xor(s2, off);
  }
  if ((tid & 63) == 0) {
    const int group = cblk * 4 + w;
    float* st = P.stats + ((size_t)(m * 2 + b) * 16 + group) * 2;
    atomicAdd(st, s);
    atomicAdd(st + 1, s2);
  }
}

// ---------------------------------------------------------------------------
// GroupNorm normalize pass, 4 float4 per thread. grid (1536), block 256.
// ---------------------------------------------------------------------------
__global__ __launch_bounds__(256) void gn_final_kernel(TP P) {
  const size_t base = ((size_t)blockIdx.x * 256 + threadIdx.x) * 4;
#pragma unroll
  for (int it = 0; it < 4; ++it) {
    const size_t idx = base + (size_t)it * 1572864;
    const int m = (int)(idx >> 21);
    const int rem = (int)(idx & ((1u << 21) - 1));
    const int b = rem >> 20;
    const int c = (rem >> 12) & 255;
    const float* st = P.stats + ((size_t)(m * 2 + b) * 16 + (c >> 4)) * 2;
    const float mean = st[0] * (1.f / 65536.f);
    const float var = st[1] * (1.f / 65536.f) - mean * mean;
    const float rstd = rsqrtf(var + EPS_);
    const float ga = P.gm[m][c] * rstd, be = P.bt[m][c];
    float4 x = *(float4*)(P.out + idx);
    x.x = (x.x - mean) * ga + be;
    x.y = (x.y - mean) * ga + be;
    x.z = (x.z - mean) * ga + be;
    x.w = (x.w - mean) * ga + be;
    *(float4*)(P.out + idx) = x;
  }
}

// ---------------------------------------------------------------------------
extern "C" void kernel_launch(void* const* d_in, const int* in_sizes, int n_in,
                              void* d_out, int out_size, void* d_ws, size_t ws_size,
                              hipStream_t stream) {
  TP P;
  for (int m = 0; m < 3; ++m) {
    P.feat[m] = (const float*)d_in[m];
    const int base = 3 + m * 10;
    P.Wq[m] = (const float*)d_in[base + 0];
    P.bq[m] = (const float*)d_in[base + 1];
    P.Wk[m] = (const float*)d_in[base + 2];
    P.bk[m] = (const float*)d_in[base + 3];
    P.Wv[m] = (const float*)d_in[base + 4];
    P.bv[m] = (const float*)d_in[base + 5];
    P.Wo[m] = (const float*)d_in[base + 6];
    P.bo[m] = (const float*)d_in[base + 7];
    P.gm[m] = (const float*)d_in[base + 8];
    P.bt[m] = (const float*)d_in[base + 9];
  }
  _Float16* ws = (_Float16*)d_ws;
  P.q16 = ws;                        // 1,572,864 halfs
  P.k16 = ws + 1572864;
  P.v16 = ws + 3145728;
  P.ao0 = ws + 4718592;
  P.ao1 = ws + 6291456;
  P.L = (float*)(ws + 7864320);      // 196,608 floats
  P.stats = (float*)(ws + 7864320) + 196608;  // 192 floats
  P.out = (float*)d_out;
  P.ctx0[0] = 1; P.ctx1[0] = 2;
  P.ctx0[1] = 0; P.ctx1[1] = 2;
  P.ctx0[2] = 0; P.ctx1[2] = 1;

  proj_fused_kernel<<<dim3(128, 2, 3), dim3(256), 0, stream>>>(P);
  attn_kernel<<<dim3(64, 8, 3), dim3(512), 0, stream>>>(P);
  wo_resid_kernel<<<dim3(64, 8, 3), dim3(256), 0, stream>>>(P);
  gn_final_kernel<<<dim3(1536), dim3(256), 0, stream>>>(P);
}